// Round 7
// baseline (35550.952 us; speedup 1.0000x reference)
//
#include <hip/hip_runtime.h>

#define B_ 128
#define T_ 256
#define H_ 512
#define O_ 256
#define X_ 768
#define NB 256
#define NT 512

typedef unsigned short u16;
typedef unsigned int u32;

#if __has_builtin(__builtin_amdgcn_exp2f)
#define EXP2(x) __builtin_amdgcn_exp2f(x)
#else
#define EXP2(x) exp2f(x)
#endif
#if __has_builtin(__builtin_amdgcn_rcpf)
#define RCPF(x) __builtin_amdgcn_rcpf(x)
#else
#define RCPF(x) (1.0f / (x))
#endif

#define LOG2E_F 1.4426950408889634f
#define TWOLOG2E_F 2.8853900817779268f

__device__ __forceinline__ float bf2f(u16 v) {
  union { u32 u; float f; } c; c.u = ((u32)v) << 16; return c.f;
}
__device__ __forceinline__ u16 f2bf(float f) {
  union { float f; u32 u; } c; c.f = f;
  return (u16)((c.u + 0x7FFFu + ((c.u >> 16) & 1u)) >> 16);
}
__device__ __forceinline__ float ftanh(float x) {
  x = fminf(fmaxf(x, -40.f), 40.f);
  float z = EXP2(x * TWOLOG2E_F);
  return (z - 1.0f) * RCPF(z + 1.0f);
}
__device__ __forceinline__ float fsigm(float x) {
  x = fminf(fmaxf(x, -40.f), 40.f);
  return RCPF(1.0f + EXP2(-x * LOG2E_F));
}

// ---- module-scope scratch ----
__device__ u16 g_hp[(size_t)B_ * T_ * H_];   // bf16 h_proj
__device__ u16 g_hb[(size_t)B_ * T_ * H_];   // bf16 copy of h
__device__ float g_sA[B_ * H_];
__device__ float g_sB[B_ * H_];
__device__ float g_x[B_ * X_];
__device__ float g_r[B_ * H_];
__device__ float g_u[B_ * H_];
__device__ int g_bar[2];

// bf16 weight copies
__device__ u16 cWy1[H_ * H_];
__device__ u16 cby1[H_];
__device__ u16 cWy2[H_ * H_];
__device__ u16 cby2[H_];
__device__ u16 cWy3[H_ * O_];
__device__ u16 cby3[O_];
__device__ u16 cWe1[2 * H_ * H_];
__device__ u16 cbe1[H_];
__device__ u16 cWe2[H_];
__device__ u16 cWxr[X_ * H_];
__device__ u16 cWhr[H_ * H_];
__device__ u16 cbr[H_];
__device__ u16 cWxu[X_ * H_];
__device__ u16 cWhu[H_ * H_];
__device__ u16 cbu[H_];
__device__ u16 cWxh[X_ * H_];
__device__ u16 cWhh[H_ * H_];

#define DEF_CONV(NAME, ARR, N)                                     \
  __global__ void conv_##NAME(const float* __restrict__ s) {       \
    int i = blockIdx.x * 256 + threadIdx.x;                        \
    if (i < (N)) ARR[i] = f2bf(s[i]);                              \
  }

DEF_CONV(Wy1, cWy1, H_ * H_)
DEF_CONV(by1, cby1, H_)
DEF_CONV(Wy2, cWy2, H_ * H_)
DEF_CONV(by2, cby2, H_)
DEF_CONV(Wy3, cWy3, H_ * O_)
DEF_CONV(by3, cby3, O_)
DEF_CONV(We1, cWe1, 2 * H_ * H_)
DEF_CONV(be1, cbe1, H_)
DEF_CONV(We2, cWe2, H_)
DEF_CONV(Wxr, cWxr, X_ * H_)
DEF_CONV(Whr, cWhr, H_ * H_)
DEF_CONV(br, cbr, H_)
DEF_CONV(Wxu, cWxu, X_ * H_)
DEF_CONV(Whu, cWhu, H_ * H_)
DEF_CONV(bu, cbu, H_)
DEF_CONV(Wxh, cWxh, X_ * H_)
DEF_CONV(Whh, cWhh, H_ * H_)

__global__ void conv_h(const float* __restrict__ s) {
  size_t i = (size_t)blockIdx.x * 256 + threadIdx.x;
  g_hb[i] = f2bf(s[i]);
}

__global__ void init_kernel(const float* __restrict__ s0) {
  int g = blockIdx.x * blockDim.x + threadIdx.x;
  if (g < B_ * H_) g_sA[g] = s0[g];
  if (g < 2) g_bar[g] = 0;
}

// ---- h_proj = h @ We1[:H]  (fp32 in, bf16 out) ----
__global__ void __launch_bounds__(256) hproj_kernel(const float* __restrict__ hh,
                                                    const float* __restrict__ We1) {
  __shared__ float Ast[32][72];
  __shared__ float Bs[32][72];
  const int tid = threadIdx.x;
  const int tx = tid & 15, ty = tid >> 4;
  const int n0 = blockIdx.x << 6;
  const int m0 = blockIdx.y << 6;
  float acc[4][4] = {};
  for (int k0 = 0; k0 < H_; k0 += 32) {
    {
      int row = tid >> 2, kq = (tid & 3) << 3;
      const float* src = hh + (size_t)(m0 + row) * H_ + k0 + kq;
      float4 v0 = *(const float4*)src;
      float4 v1 = *(const float4*)(src + 4);
      Ast[kq + 0][row] = v0.x; Ast[kq + 1][row] = v0.y;
      Ast[kq + 2][row] = v0.z; Ast[kq + 3][row] = v0.w;
      Ast[kq + 4][row] = v1.x; Ast[kq + 5][row] = v1.y;
      Ast[kq + 6][row] = v1.z; Ast[kq + 7][row] = v1.w;
    }
    {
      int kr = tid >> 3, nq = (tid & 7) << 3;
      const float* src = We1 + (size_t)(k0 + kr) * H_ + n0 + nq;
      float4 v0 = *(const float4*)src;
      float4 v1 = *(const float4*)(src + 4);
      float* d = &Bs[kr][nq];
      d[0] = v0.x; d[1] = v0.y; d[2] = v0.z; d[3] = v0.w;
      d[4] = v1.x; d[5] = v1.y; d[6] = v1.z; d[7] = v1.w;
    }
    __syncthreads();
#pragma unroll
    for (int kk = 0; kk < 32; ++kk) {
      const float4 a4 = *(const float4*)&Ast[kk][ty << 2];
      const float4 b4 = *(const float4*)&Bs[kk][tx << 2];
      float av[4] = {a4.x, a4.y, a4.z, a4.w};
      float bv[4] = {b4.x, b4.y, b4.z, b4.w};
#pragma unroll
      for (int i = 0; i < 4; ++i)
#pragma unroll
        for (int j = 0; j < 4; ++j) acc[i][j] = fmaf(av[i], bv[j], acc[i][j]);
    }
    __syncthreads();
  }
#pragma unroll
  for (int i = 0; i < 4; ++i) {
    u16* dst = g_hp + (size_t)(m0 + ty * 4 + i) * H_ + n0 + tx * 4;
    u32 w0 = (u32)f2bf(acc[i][0]) | ((u32)f2bf(acc[i][1]) << 16);
    u32 w1 = (u32)f2bf(acc[i][2]) | ((u32)f2bf(acc[i][3]) << 16);
    *(u32*)dst = w0;
    *(u32*)(dst + 2) = w1;
  }
}

#define FMA8(pk, sk, A)                                          \
  {                                                              \
    u32 ww0 = pk.x, ww1 = pk.y, ww2 = pk.z, ww3 = pk.w;          \
    A[0] = fmaf(sk, bf2f((u16)(ww0 & 0xffffu)), A[0]);           \
    A[1] = fmaf(sk, bf2f((u16)(ww0 >> 16)), A[1]);               \
    A[2] = fmaf(sk, bf2f((u16)(ww1 & 0xffffu)), A[2]);           \
    A[3] = fmaf(sk, bf2f((u16)(ww1 >> 16)), A[3]);               \
    A[4] = fmaf(sk, bf2f((u16)(ww2 & 0xffffu)), A[4]);           \
    A[5] = fmaf(sk, bf2f((u16)(ww2 >> 16)), A[5]);               \
    A[6] = fmaf(sk, bf2f((u16)(ww3 & 0xffffu)), A[6]);           \
    A[7] = fmaf(sk, bf2f((u16)(ww3 >> 16)), A[7]);               \
  }

// ---- grid barrier (R1-proven sense-reversing, agent scope) ----
__device__ __forceinline__ void grid_barrier() {
  __syncthreads();
  if (threadIdx.x == 0) {
    __threadfence();
    int g = __hip_atomic_load(&g_bar[1], __ATOMIC_RELAXED, __HIP_MEMORY_SCOPE_AGENT);
    int prev = __hip_atomic_fetch_add(&g_bar[0], 1, __ATOMIC_ACQ_REL, __HIP_MEMORY_SCOPE_AGENT);
    if (prev == NB - 1) {
      __hip_atomic_store(&g_bar[0], 0, __ATOMIC_RELAXED, __HIP_MEMORY_SCOPE_AGENT);
      __hip_atomic_store(&g_bar[1], g + 1, __ATOMIC_RELEASE, __HIP_MEMORY_SCOPE_AGENT);
    } else {
      while (__hip_atomic_load(&g_bar[1], __ATOMIC_RELAXED, __HIP_MEMORY_SCOPE_AGENT) == g)
        __builtin_amdgcn_s_sleep(2);
    }
    __threadfence();
  }
  __syncthreads();
}

// ---- persistent main: 256 steps, 3 grid barriers/step ----
#define PT 1536
__global__ void __launch_bounds__(NT, 1) rnn_main(float* __restrict__ out) {
  __shared__ __align__(16) float sm[9216];
  __shared__ float red[16];
  __shared__ float w2s[512];
  const int tid = threadIdx.x;
  const int blk = blockIdx.x;
  const int b    = ((blk >> 4) << 3) | (blk & 7);
  const int half = (blk >> 3) & 1;
  const int b0 = (blk >> 3) << 2, j8 = blk & 7;

  for (int t = 0; t < T_; ++t) {
    const float* scur = (t & 1) ? g_sB : g_sA;
    float* snxt       = (t & 1) ? g_sA : g_sB;

    // ================= Seg1 (R6 k_step1 body) =================
    sm[tid] = scur[b * H_ + tid];
    if (half) w2s[tid] = bf2f(cWe2[tid]);
    __syncthreads();

    if (half == 0) {
      const int c = tid & 63, ks = tid >> 6;
      const int n0 = c << 3, kb = ks << 6;
      {
        float a[8] = {};
        const u16* w = cWy1 + (size_t)kb * H_ + n0;
#pragma unroll 4
        for (int k = 0; k < 64; ++k) {
          uint4 pk = *(const uint4*)(w + (size_t)k * H_);
          float sk = sm[kb + k];
          FMA8(pk, sk, a);
        }
        float* pt = &sm[PT + ks * 512 + n0];
#pragma unroll
        for (int j = 0; j < 8; ++j) pt[j] = a[j];
      }
      __syncthreads();
      {
        float v = bf2f(cby1[tid]);
#pragma unroll
        for (int kk = 0; kk < 8; ++kk) v += sm[PT + kk * 512 + tid];
        sm[512 + tid] = ftanh(v);
      }
      __syncthreads();
      {
        float a[8] = {};
        const u16* w = cWy2 + (size_t)kb * H_ + n0;
#pragma unroll 4
        for (int k = 0; k < 64; ++k) {
          uint4 pk = *(const uint4*)(w + (size_t)k * H_);
          float sk = sm[512 + kb + k];
          FMA8(pk, sk, a);
        }
        float* pt = &sm[PT + ks * 512 + n0];
#pragma unroll
        for (int j = 0; j < 8; ++j) pt[j] = a[j];
      }
      __syncthreads();
      {
        float v = bf2f(cby2[tid]);
#pragma unroll
        for (int kk = 0; kk < 8; ++kk) v += sm[PT + kk * 512 + tid];
        sm[tid] = ftanh(v);
      }
      __syncthreads();
      {
        const int c3 = tid & 31, ks3 = tid >> 5;
        const int m0 = c3 << 3, kb3 = ks3 << 5;
        float a[8] = {};
        const u16* w = cWy3 + (size_t)kb3 * O_ + m0;
#pragma unroll 4
        for (int k = 0; k < 32; ++k) {
          uint4 pk = *(const uint4*)(w + (size_t)k * O_);
          float sk = sm[kb3 + k];
          FMA8(pk, sk, a);
        }
        float* pt = &sm[PT + ks3 * 256 + m0];
#pragma unroll
        for (int j = 0; j < 8; ++j) pt[j] = a[j];
      }
      __syncthreads();
      if (tid < O_) {
        float v = bf2f(cby3[tid]);
#pragma unroll
        for (int kk = 0; kk < 16; ++kk) v += sm[PT + kk * 256 + tid];
        g_x[b * X_ + tid] = v;
        out[((size_t)b * T_ + t) * O_ + tid] = v;
      }
    } else {
      const int c = tid & 63, ks = tid >> 6;
      const int n0 = c << 3, kb = ks << 6;
      {
        float a[8] = {};
        const u16* w = cWe1 + (size_t)(H_ + kb) * H_ + n0;
#pragma unroll 4
        for (int k = 0; k < 64; ++k) {
          uint4 pk = *(const uint4*)(w + (size_t)k * H_);
          float sk = sm[kb + k];
          FMA8(pk, sk, a);
        }
        float* pt = &sm[PT + ks * 512 + n0];
#pragma unroll
        for (int j = 0; j < 8; ++j) pt[j] = a[j];
      }
      __syncthreads();
      {
        float v = bf2f(cbe1[tid]);
#pragma unroll
        for (int kk = 0; kk < 8; ++kk) v += sm[PT + kk * 512 + tid];
        sm[512 + tid] = v;
      }
      __syncthreads();
      const int wv = tid >> 6, ln = tid & 63;
      {
        const float* spb = &sm[512 + (ln << 3)];
        const float* w2b = &w2s[ln << 3];
        for (int tp = wv; tp < T_; tp += 8) {
          const u16* hpp = g_hp + ((size_t)(b * T_ + tp) << 9) + (ln << 3);
          uint4 pk = *(const uint4*)hpp;
          u32 ww[4] = {pk.x, pk.y, pk.z, pk.w};
          float part = 0.f;
#pragma unroll
          for (int jj = 0; jj < 4; ++jj) {
            float lo = bf2f((u16)(ww[jj] & 0xffffu));
            float hi = bf2f((u16)(ww[jj] >> 16));
            float a0 = fminf((lo + spb[2 * jj]) * TWOLOG2E_F, 80.f);
            float a1 = fminf((hi + spb[2 * jj + 1]) * TWOLOG2E_F, 80.f);
            float z0 = EXP2(a0), z1 = EXP2(a1);
            float t0 = (z0 - 1.f) * RCPF(z0 + 1.f);
            float t1 = (z1 - 1.f) * RCPF(z1 + 1.f);
            part = fmaf(t0, w2b[2 * jj], part);
            part = fmaf(t1, w2b[2 * jj + 1], part);
          }
#pragma unroll
          for (int off = 32; off > 0; off >>= 1) part += __shfl_down(part, off, 64);
          if (ln == 0) sm[1024 + tp] = part;
        }
      }
      __syncthreads();
      float v = (tid < T_) ? sm[1024 + tid] : -3.0e38f;
      float m = v;
#pragma unroll
      for (int off = 32; off > 0; off >>= 1) m = fmaxf(m, __shfl_xor(m, off, 64));
      if (ln == 0) red[wv] = m;
      __syncthreads();
      m = fmaxf(fmaxf(fmaxf(red[0], red[1]), fmaxf(red[2], red[3])),
                fmaxf(fmaxf(red[4], red[5]), fmaxf(red[6], red[7])));
      float pe = (tid < T_) ? EXP2((v - m) * LOG2E_F) : 0.f;
      float ssum = pe;
#pragma unroll
      for (int off = 32; off > 0; off >>= 1) ssum += __shfl_xor(ssum, off, 64);
      if (ln == 0) red[8 + wv] = ssum;
      __syncthreads();
      float tot = (red[8] + red[9]) + (red[10] + red[11]) +
                  (red[12] + red[13]) + (red[14] + red[15]);
      float ainv = RCPF(tot);
      if (tid < T_) sm[1024 + tid] = pe * ainv;
      __syncthreads();
      {
        const int ts = tid >> 6;
        float a[8] = {};
        const u16* hb = g_hb + (size_t)b * T_ * H_ + n0;
#pragma unroll 4
        for (int tp = ts * 32; tp < ts * 32 + 32; ++tp) {
          uint4 pk = *(const uint4*)(hb + (size_t)tp * H_);
          float av = sm[1024 + tp];
          FMA8(pk, av, a);
        }
        float* pt = &sm[PT + ts * 512 + n0];
#pragma unroll
        for (int j = 0; j < 8; ++j) pt[j] = a[j];
      }
      __syncthreads();
      {
        float v2 = 0.f;
#pragma unroll
        for (int kk = 0; kk < 8; ++kk) v2 += sm[PT + kk * 512 + tid];
        g_x[b * X_ + O_ + tid] = v2;
      }
    }
    grid_barrier();

    // ================= Seg2: r|u = sigmoid(x@Wx + s@Wh + b) =================
    for (int i = tid; i < 5120; i += NT) {
      int k = i >> 2, bl = i & 3;
      sm[i] = (k < X_) ? g_x[(b0 + bl) * X_ + k] : scur[(b0 + bl) * H_ + (k - X_)];
    }
    __syncthreads();
    {
      const int bl = tid & 3, cu = (tid >> 2) & 15, ks = tid >> 6;  // 16 cu, 8 ks
      const int col = (j8 << 7) + (cu << 3);                        // 0..1023
      const bool isU = (col >= H_);
      const int n0 = isU ? (col - H_) : col;
      const u16* Wx = isU ? cWxu : cWxr;
      const u16* Wh = isU ? cWhu : cWhr;
      float a[8] = {};
      const int k0 = ks * 160, k1 = k0 + 160;
      const int kxe = (k1 < X_) ? k1 : X_;
#pragma unroll 4
      for (int k = k0; k < kxe; ++k) {
        uint4 pk = *(const uint4*)(Wx + (size_t)k * H_ + n0);
        float xk = sm[(k << 2) + bl];
        FMA8(pk, xk, a);
      }
      const int khs = (k0 > X_) ? k0 : X_;
#pragma unroll 4
      for (int k = khs; k < k1; ++k) {
        uint4 pk = *(const uint4*)(Wh + (size_t)(k - X_) * H_ + n0);
        float xk = sm[(k << 2) + bl];
        FMA8(pk, xk, a);
      }
#pragma unroll
      for (int j = 0; j < 8; ++j)
        sm[5120 + ks * 512 + ((cu << 3) + j) * 4 + bl] = a[j];
    }
    __syncthreads();
    {
      const int c = tid >> 2, bl = tid & 3;   // c 0..127
      const int col = (j8 << 7) + c;
      const bool isU = (col >= H_);
      const int n = isU ? (col - H_) : col;
      float v = bf2f((isU ? cbu : cbr)[n]);
#pragma unroll
      for (int kk = 0; kk < 8; ++kk) v += sm[5120 + kk * 512 + c * 4 + bl];
      (isU ? g_u : g_r)[(b0 + bl) * H_ + n] = fsigm(v);
    }
    grid_barrier();

    // ================= Seg3: h_cand = tanh(x@Wxh + (r*s)@Whh) =================
    for (int i = tid; i < 5120; i += NT) {
      int k = i >> 2, bl = i & 3;
      float vv;
      if (k < X_) vv = g_x[(b0 + bl) * X_ + k];
      else { int idx = (b0 + bl) * H_ + (k - X_); vv = g_r[idx] * scur[idx]; }
      sm[i] = vv;
    }
    __syncthreads();
    {
      const int bl = tid & 3, cu = (tid >> 2) & 7, ks = tid >> 5;  // 8 cu, 16 ks
      const int n0 = (j8 << 6) + (cu << 3);                        // 0..511
      float a[8] = {};
      const int k0 = ks * 80, k1 = k0 + 80;
      const int kxe = (k1 < X_) ? k1 : X_;
#pragma unroll 4
      for (int k = k0; k < kxe; ++k) {
        uint4 pk = *(const uint4*)(cWxh + (size_t)k * H_ + n0);
        float xk = sm[(k << 2) + bl];
        FMA8(pk, xk, a);
      }
      const int khs = (k0 > X_) ? k0 : X_;
#pragma unroll 4
      for (int k = khs; k < k1; ++k) {
        uint4 pk = *(const uint4*)(cWhh + (size_t)(k - X_) * H_ + n0);
        float xk = sm[(k << 2) + bl];
        FMA8(pk, xk, a);
      }
#pragma unroll
      for (int j = 0; j < 8; ++j)
        sm[5120 + ks * 256 + ((cu << 3) + j) * 4 + bl] = a[j];
    }
    __syncthreads();
    if (tid < 256) {
      const int c = tid >> 2, bl = tid & 3;   // c 0..63
      const int col = (j8 << 6) + c;
      float v = 0.f;
#pragma unroll
      for (int kk = 0; kk < 16; ++kk) v += sm[5120 + kk * 256 + c * 4 + bl];
      float hc = ftanh(v);
      int idx = (b0 + bl) * H_ + col;
      float uu = g_u[idx];
      snxt[idx] = (1.f - uu) * hc + uu * scur[idx];
    }
    grid_barrier();
  }
}

extern "C" void kernel_launch(void* const* d_in, const int* in_sizes, int n_in,
                              void* d_out, int out_size, void* d_ws, size_t ws_size,
                              hipStream_t stream) {
  (void)in_sizes; (void)n_in; (void)out_size; (void)d_ws; (void)ws_size;
  const float* h  = (const float*)d_in[0];
  const float* s0 = (const float*)d_in[1];
  float* out = (float*)d_out;

#define CONV(NAME, IDX, N) \
  hipLaunchKernelGGL(conv_##NAME, dim3(((N) + 255) / 256), dim3(256), 0, stream, \
                     (const float*)d_in[IDX])
  CONV(Wy1, 2, H_ * H_);
  CONV(by1, 3, H_);
  CONV(Wy2, 4, H_ * H_);
  CONV(by2, 5, H_);
  CONV(Wy3, 6, H_ * O_);
  CONV(by3, 7, O_);
  CONV(We1, 8, 2 * H_ * H_);
  CONV(be1, 9, H_);
  CONV(We2, 10, H_);
  // d_in[11] = be2: softmax shift-invariant, unused
  CONV(Wxr, 12, X_ * H_);
  CONV(Whr, 13, H_ * H_);
  CONV(br, 14, H_);
  CONV(Wxu, 15, X_ * H_);
  CONV(Whu, 16, H_ * H_);
  CONV(bu, 17, H_);
  CONV(Wxh, 18, X_ * H_);
  CONV(Whh, 19, H_ * H_);
#undef CONV
  hipLaunchKernelGGL(conv_h, dim3((B_ * T_ * H_) / 256), dim3(256), 0, stream, h);
  hipLaunchKernelGGL(init_kernel, dim3(256), dim3(256), 0, stream, s0);
  hipLaunchKernelGGL(hproj_kernel, dim3(8, 512), dim3(256), 0, stream, h,
                     (const float*)d_in[8]);

  void* args[] = { &out };
  hipLaunchCooperativeKernel(reinterpret_cast<void*>(&rnn_main), dim3(NB), dim3(NT),
                             args, 0, stream);
}